// Round 8
// baseline (342.932 us; speedup 1.0000x reference)
//
#include <hip/hip_runtime.h>

typedef unsigned short ushort_t;
typedef __bf16 bf16x8 __attribute__((ext_vector_type(8)));
typedef float f4v __attribute__((ext_vector_type(4)));

#define B_ 2
#define T_ 4096
#define C_ 768
#define H_ 12
#define D_ 64
#define BT_ (B_*T_)

// workspace layout (bytes)
#define XB_SZ   (BT_*C_*2)
#define WT_SZ   (C_*C_*2)
#define QKV_SZ  (BT_*C_*2)
#define WS_XB   0
#define WS_WT   (WS_XB + XB_SZ)
#define WS_Q    (WS_WT + 4*WT_SZ)
#define WS_K    (WS_Q + QKV_SZ)
#define WS_V    (WS_K + QKV_SZ)
#define WS_AO   (WS_V + QKV_SZ)
#define WS_TOTAL (WS_AO + QKV_SZ)

// log2(e) folded into Q scale so softmax exp() becomes exp2()
#define QSCALE  0.18033688f   // 0.125 * 1.44269504

__device__ __forceinline__ ushort_t f2bf(float f) {
    unsigned u = __float_as_uint(f);
    u += 0x7FFFu + ((u >> 16) & 1u);
    return (ushort_t)(u >> 16);
}

// async global->LDS, 16B per lane; ldst must be wave-uniform (HW adds lane*16)
__device__ __forceinline__ void gload16(const void* gsrc, void* ldst) {
    __builtin_amdgcn_global_load_lds(
        (const __attribute__((address_space(1))) unsigned int*)gsrc,
        (__attribute__((address_space(3))) unsigned int*)ldst, 16, 0, 0);
}

__global__ __launch_bounds__(256) void k_convert_x(const float* __restrict__ x,
                                                   ushort_t* __restrict__ xb, int n4) {
    int i = blockIdx.x * 256 + threadIdx.x;
    if (i >= n4) return;
    float4 v = ((const float4*)x)[i];
    ushort4 o;
    o.x = f2bf(v.x); o.y = f2bf(v.y); o.z = f2bf(v.z); o.w = f2bf(v.w);
    ((ushort4*)xb)[i] = o;
}

// Wt[n][k] = bf16(W[k][n]), four weights
__global__ __launch_bounds__(256) void k_wt(const float* __restrict__ w0,
                                            const float* __restrict__ w1,
                                            const float* __restrict__ w2,
                                            const float* __restrict__ w3,
                                            ushort_t* __restrict__ wt) {
    __shared__ float tile[32][33];
    int wi = blockIdx.z;
    const float* W = (wi == 0) ? w0 : (wi == 1) ? w1 : (wi == 2) ? w2 : w3;
    ushort_t* out = wt + wi * C_ * C_;
    int k0 = blockIdx.x * 32, n0 = blockIdx.y * 32;
    int tx = threadIdx.x & 31, ty = threadIdx.x >> 5;
#pragma unroll
    for (int i = 0; i < 4; ++i) {
        int kr = ty * 4 + i;
        tile[kr][tx] = W[(k0 + kr) * C_ + n0 + tx];
    }
    __syncthreads();
#pragma unroll
    for (int i = 0; i < 4; ++i) {
        int nr = ty * 4 + i;
        out[(n0 + nr) * C_ + k0 + tx] = f2bf(tile[tx][nr]);
    }
}

// 128x128 tile GEMM, 4 waves (2x2); BK=64; global_load_lds staging with
// inverse-swizzled source (linear LDS dest, swizzled read: rule #21).
// z=0:Q (scaled QSCALE), z=1:K, z=2:V stored transposed [B,H,D,T]
__global__ __launch_bounds__(256) void k_gemm_qkv(
    const ushort_t* __restrict__ Xb, const ushort_t* __restrict__ WtAll,
    const float* __restrict__ bq, const float* __restrict__ bk, const float* __restrict__ bv,
    ushort_t* __restrict__ Qo, ushort_t* __restrict__ Ko, ushort_t* __restrict__ Vo) {
    __shared__ ushort_t lsA[128 * 64];
    __shared__ ushort_t lsB[128 * 64];
    char* lsAb = (char*)lsA;
    char* lsBb = (char*)lsB;
    const int z = blockIdx.z;
    const ushort_t* Wt = WtAll + z * C_ * C_;
    const float* bias = (z == 0) ? bq : (z == 1) ? bk : bv;
    const int m0 = blockIdx.x * 128, n0 = blockIdx.y * 128;
    const int tid = threadIdx.x;
    const int w = tid >> 6, lane = tid & 63, lg = lane >> 4, lr = lane & 15;
    const int wm = w >> 1, wn = w & 1;
    f4v acc[4][4] = {};
    for (int ks = 0; ks < 12; ++ks) {
        const int k0 = ks * 64;
        __syncthreads();
#pragma unroll
        for (int i = 0; i < 4; ++i) {
            int s = tid + 256 * i;
            int r = s >> 3, cs = (s & 7) ^ (r & 7);   // inverse-swizzled source col
            gload16(Xb + (m0 + r) * C_ + k0 + cs * 8, lsAb + i * 4096 + w * 1024);
            gload16(Wt + (n0 + r) * C_ + k0 + cs * 8, lsBb + i * 4096 + w * 1024);
        }
        __syncthreads();
#pragma unroll
        for (int kk = 0; kk < 2; ++kk) {
            bf16x8 af[4], bfr[4];
            const int kb = (kk * 32 + lg * 8) * 2;
#pragma unroll
            for (int i = 0; i < 4; ++i) {
                int ra = wm * 64 + i * 16 + lr;
                af[i] = *(const bf16x8*)(lsAb + ra * 128 + (kb ^ ((ra & 7) << 4)));
                int rb = wn * 64 + i * 16 + lr;
                bfr[i] = *(const bf16x8*)(lsBb + rb * 128 + (kb ^ ((rb & 7) << 4)));
            }
#pragma unroll
            for (int mi = 0; mi < 4; ++mi)
#pragma unroll
                for (int nj = 0; nj < 4; ++nj)
                    acc[mi][nj] = __builtin_amdgcn_mfma_f32_16x16x32_bf16(af[mi], bfr[nj], acc[mi][nj], 0, 0, 0);
        }
    }
    const float scale = (z == 0) ? QSCALE : 1.0f;
    const int mbase = m0 + wm * 64, nbase = n0 + wn * 64;
    if (z < 2) {
        ushort_t* outp = (z == 0) ? Qo : Ko;
#pragma unroll
        for (int mi = 0; mi < 4; ++mi) {
#pragma unroll
            for (int nj = 0; nj < 4; ++nj) {
                int col = nbase + nj * 16 + lr;
                int h = col >> 6, d = col & 63;
                float bv_ = bias[col];
#pragma unroll
                for (int j = 0; j < 4; ++j) {
                    int m = mbase + mi * 16 + lg * 4 + j;
                    int bb = m >> 12, t = m & 4095;
                    outp[((bb * H_ + h) * T_ + t) * D_ + d] = f2bf((acc[mi][nj][j] + bv_) * scale);
                }
            }
        }
    } else {
        // V stored transposed: Vo[((b*H+h)*D + d)*T + t]
#pragma unroll
        for (int mi = 0; mi < 4; ++mi) {
            int m0j = mbase + mi * 16 + lg * 4;
            int bb = m0j >> 12, t0 = m0j & 4095;
#pragma unroll
            for (int nj = 0; nj < 4; ++nj) {
                int col = nbase + nj * 16 + lr;
                int h = col >> 6, d = col & 63;
                float bv_ = bias[col];
                ushort4 pk;
                pk.x = f2bf(acc[mi][nj][0] + bv_);
                pk.y = f2bf(acc[mi][nj][1] + bv_);
                pk.z = f2bf(acc[mi][nj][2] + bv_);
                pk.w = f2bf(acc[mi][nj][3] + bv_);
                *(ushort4*)(Vo + ((size_t)(bb * H_ + h) * D_ + d) * T_ + t0) = pk;
            }
        }
    }
}

// flash attention: paired-qt grid for perfect balance.
// grid = 768 blocks: bh = idx%24, pi = idx/24 (0..31); block does qt=63-pi then qt=pi
// -> exactly 65 KV-tiles per block. 4 waves x 16 q-rows; KVBLK=64.
// V input is transposed [B,H,D,T]. exp2-domain softmax (log2e folded into Q).
__global__ __launch_bounds__(256) void k_flash(const ushort_t* __restrict__ Q,
                                               const ushort_t* __restrict__ K,
                                               const ushort_t* __restrict__ Vt,
                                               ushort_t* __restrict__ AO) {
    __shared__ ushort_t lsK[64 * 64];
    __shared__ ushort_t lsV[64 * 64];
    __shared__ ushort_t lsP[4 * 16 * 64];
    char* lsKb = (char*)lsK;
    char* lsVb = (char*)lsV;
    const int idx = blockIdx.x;
    const int pi = idx / 24;
    const int bh = idx % 24;
    const int b = bh / H_, h = bh % H_;
    const int tid = threadIdx.x, w = tid >> 6, lane = tid & 63, lg = lane >> 4, lr = lane & 15;
    char* lsPb = (char*)(lsP + w * 16 * 64);
    const ushort_t* qb = Q + (size_t)bh * T_ * D_;
    const ushort_t* kb = K + (size_t)bh * T_ * D_;
    const ushort_t* vtb = Vt + (size_t)bh * D_ * T_;   // [D][T]
    ushort_t* aob = AO + (size_t)b * T_ * C_ + h * D_;

    for (int half = 0; half < 2; ++half) {
        const int qt = half ? pi : (63 - pi);
        const int q0 = qt * 64;
        const int wave_qmin = q0 + w * 16;
        bf16x8 aq[2];
#pragma unroll
        for (int kk = 0; kk < 2; ++kk)
            aq[kk] = *(const bf16x8*)(qb + (size_t)(wave_qmin + lr) * D_ + kk * 32 + lg * 8);
        float m_s[4], l_s[4];
        f4v o[4] = {};
#pragma unroll
        for (int j = 0; j < 4; ++j) { m_s[j] = -1e30f; l_s[j] = 0.f; }

        const int ntiles = qt + 1;
        for (int kt = 0; kt < ntiles; ++kt) {
            const int kv0 = kt * 64;
            __syncthreads();
            // async stage K rows [kv][d] and V^T rows [d][kv]; LDS linear dest,
            // inverse-swizzled global source (read-side XOR matches)
#pragma unroll
            for (int i = 0; i < 2; ++i) {
                int s = tid + 256 * i;
                int r = s >> 3, cs = (s & 7) ^ (r & 7);
                gload16(kb + (size_t)(kv0 + r) * D_ + cs * 8, lsKb + i * 4096 + w * 1024);
                gload16(vtb + (size_t)r * T_ + kv0 + cs * 8, lsVb + i * 4096 + w * 1024);
            }
            __syncthreads();
            // S = Q K^T  (16 q-rows x 64 kv)
            f4v sf[4] = {};
#pragma unroll
            for (int kk = 0; kk < 2; ++kk) {
                const int kbyte = (kk * 32 + lg * 8) * 2;
                bf16x8 bk_[4];
#pragma unroll
                for (int nt = 0; nt < 4; ++nt) {
                    int rk = nt * 16 + lr;
                    bk_[nt] = *(const bf16x8*)(lsKb + rk * 128 + (kbyte ^ ((rk & 7) << 4)));
                }
                __builtin_amdgcn_s_setprio(1);
#pragma unroll
                for (int nt = 0; nt < 4; ++nt)
                    sf[nt] = __builtin_amdgcn_mfma_f32_16x16x32_bf16(aq[kk], bk_[nt], sf[nt], 0, 0, 0);
                __builtin_amdgcn_s_setprio(0);
            }
            if (kv0 + 63 > wave_qmin) {  // diagonal tile: causal mask, finite sentinel
#pragma unroll
                for (int nt = 0; nt < 4; ++nt)
#pragma unroll
                    for (int j = 0; j < 4; ++j) {
                        int qg = wave_qmin + lg * 4 + j;
                        int kg = kv0 + nt * 16 + lr;
                        if (kg > qg) sf[nt][j] = -1e30f;
                    }
            }
            // online softmax in exp2 domain (wave-parallel 16-lane butterflies)
#pragma unroll
            for (int j = 0; j < 4; ++j) {
                float rm = fmaxf(fmaxf(sf[0][j], sf[1][j]), fmaxf(sf[2][j], sf[3][j]));
                rm = fmaxf(rm, __shfl_xor(rm, 1));
                rm = fmaxf(rm, __shfl_xor(rm, 2));
                rm = fmaxf(rm, __shfl_xor(rm, 4));
                rm = fmaxf(rm, __shfl_xor(rm, 8));
                float mo = m_s[j];
                float mn = fmaxf(mo, rm);
                float alpha = exp2f(mo - mn);
                float rs = 0.f;
                int prow = lg * 4 + j;
#pragma unroll
                for (int nt = 0; nt < 4; ++nt) {
                    float p = exp2f(sf[nt][j] - mn);
                    rs += p;
                    int cbyte = (nt * 16 + lr) * 2;
                    *(ushort_t*)(lsPb + prow * 128 + (cbyte ^ ((prow & 7) << 4))) = f2bf(p);
                }
                rs += __shfl_xor(rs, 1);
                rs += __shfl_xor(rs, 2);
                rs += __shfl_xor(rs, 4);
                rs += __shfl_xor(rs, 8);
                l_s[j] = l_s[j] * alpha + rs;
                m_s[j] = mn;
#pragma unroll
                for (int nt = 0; nt < 4; ++nt) o[nt][j] *= alpha;
            }
            // O += P V  (A-frag from lsP, B-frags from lsV = V^T)
#pragma unroll
            for (int kk = 0; kk < 2; ++kk) {
                const int kvbyte = (kk * 32 + lg * 8) * 2;
                bf16x8 ap, bv_[4];
                ap = *(const bf16x8*)(lsPb + lr * 128 + (kvbyte ^ ((lr & 7) << 4)));
#pragma unroll
                for (int nt = 0; nt < 4; ++nt) {
                    int rd = nt * 16 + lr;
                    bv_[nt] = *(const bf16x8*)(lsVb + rd * 128 + (kvbyte ^ ((rd & 7) << 4)));
                }
                __builtin_amdgcn_s_setprio(1);
#pragma unroll
                for (int nt = 0; nt < 4; ++nt)
                    o[nt] = __builtin_amdgcn_mfma_f32_16x16x32_bf16(ap, bv_[nt], o[nt], 0, 0, 0);
                __builtin_amdgcn_s_setprio(0);
            }
        }
        // epilogue: normalize + store to [B,T,C] bf16
#pragma unroll
        for (int j = 0; j < 4; ++j) {
            float inv = 1.f / l_s[j];
            int qg = wave_qmin + lg * 4 + j;
#pragma unroll
            for (int nt = 0; nt < 4; ++nt) {
                int d = nt * 16 + lr;
                aob[(size_t)qg * C_ + d] = f2bf(o[nt][j] * inv);
            }
        }
    }
}

// final projection: fp32 out = AO @ Wo^T(stored) + bo
__global__ __launch_bounds__(256) void k_gemm_out(const ushort_t* __restrict__ Ab,
                                                  const ushort_t* __restrict__ Wt,
                                                  const float* __restrict__ bo,
                                                  float* __restrict__ Out) {
    __shared__ ushort_t lsA[128 * 64];
    __shared__ ushort_t lsB[128 * 64];
    char* lsAb = (char*)lsA;
    char* lsBb = (char*)lsB;
    const int m0 = blockIdx.x * 128, n0 = blockIdx.y * 128;
    const int tid = threadIdx.x;
    const int w = tid >> 6, lane = tid & 63, lg = lane >> 4, lr = lane & 15;
    const int wm = w >> 1, wn = w & 1;
    f4v acc[4][4] = {};
    for (int ks = 0; ks < 12; ++ks) {
        const int k0 = ks * 64;
        __syncthreads();
#pragma unroll
        for (int i = 0; i < 4; ++i) {
            int s = tid + 256 * i;
            int r = s >> 3, cs = (s & 7) ^ (r & 7);
            gload16(Ab + (m0 + r) * C_ + k0 + cs * 8, lsAb + i * 4096 + w * 1024);
            gload16(Wt + (n0 + r) * C_ + k0 + cs * 8, lsBb + i * 4096 + w * 1024);
        }
        __syncthreads();
#pragma unroll
        for (int kk = 0; kk < 2; ++kk) {
            bf16x8 af[4], bfr[4];
            const int kb = (kk * 32 + lg * 8) * 2;
#pragma unroll
            for (int i = 0; i < 4; ++i) {
                int ra = wm * 64 + i * 16 + lr;
                af[i] = *(const bf16x8*)(lsAb + ra * 128 + (kb ^ ((ra & 7) << 4)));
                int rb = wn * 64 + i * 16 + lr;
                bfr[i] = *(const bf16x8*)(lsBb + rb * 128 + (kb ^ ((rb & 7) << 4)));
            }
#pragma unroll
            for (int mi = 0; mi < 4; ++mi)
#pragma unroll
                for (int nj = 0; nj < 4; ++nj)
                    acc[mi][nj] = __builtin_amdgcn_mfma_f32_16x16x32_bf16(af[mi], bfr[nj], acc[mi][nj], 0, 0, 0);
        }
    }
    const int mbase = m0 + wm * 64, nbase = n0 + wn * 64;
#pragma unroll
    for (int mi = 0; mi < 4; ++mi) {
#pragma unroll
        for (int nj = 0; nj < 4; ++nj) {
            int col = nbase + nj * 16 + lr;
            float bv_ = bo[col];
#pragma unroll
            for (int j = 0; j < 4; ++j) {
                int m = mbase + mi * 16 + lg * 4 + j;
                Out[(size_t)m * C_ + col] = acc[mi][nj][j] + bv_;
            }
        }
    }
}

extern "C" void kernel_launch(void* const* d_in, const int* in_sizes, int n_in,
                              void* d_out, int out_size, void* d_ws, size_t ws_size,
                              hipStream_t stream) {
    const float* x  = (const float*)d_in[0];
    const float* Wq = (const float*)d_in[1];
    const float* bq = (const float*)d_in[2];
    const float* Wk = (const float*)d_in[3];
    const float* bk = (const float*)d_in[4];
    const float* Wv = (const float*)d_in[5];
    const float* bv = (const float*)d_in[6];
    const float* Wo = (const float*)d_in[7];
    const float* bo = (const float*)d_in[8];
    float* out = (float*)d_out;
    char* ws = (char*)d_ws;
    if (ws_size < (size_t)WS_TOTAL) return;

    ushort_t* Xb = (ushort_t*)(ws + WS_XB);
    ushort_t* Wt = (ushort_t*)(ws + WS_WT);
    ushort_t* Qb = (ushort_t*)(ws + WS_Q);
    ushort_t* Kb = (ushort_t*)(ws + WS_K);
    ushort_t* Vb = (ushort_t*)(ws + WS_V);
    ushort_t* Ao = (ushort_t*)(ws + WS_AO);

    k_convert_x<<<dim3(BT_ * C_ / 4 / 256), 256, 0, stream>>>(x, Xb, BT_ * C_ / 4);
    k_wt<<<dim3(24, 24, 4), 256, 0, stream>>>(Wq, Wk, Wv, Wo, Wt);
    k_gemm_qkv<<<dim3(64, 6, 3), 256, 0, stream>>>(Xb, Wt, bq, bk, bv, Qb, Kb, Vb);
    k_flash<<<dim3(32 * 24), 256, 0, stream>>>(Qb, Kb, Vb, Ao);
    k_gemm_out<<<dim3(64, 6), 256, 0, stream>>>(Ao, Wt + 3 * C_ * C_, bo, out);
}

// Round 9
// 289.844 us; speedup vs baseline: 1.1832x; 1.1832x over previous
//
#include <hip/hip_runtime.h>
#include <hip/hip_bf16.h>

typedef unsigned short ushort_t;
typedef __bf16 bf16x8 __attribute__((ext_vector_type(8)));
typedef float f4v __attribute__((ext_vector_type(4)));

#define B_ 2
#define T_ 4096
#define C_ 768
#define H_ 12
#define D_ 64
#define BT_ (B_*T_)

// workspace layout (bytes)
#define XB_SZ   (BT_*C_*2)
#define WT_SZ   (C_*C_*2)
#define QKV_SZ  (BT_*C_*2)
#define WS_XB   0
#define WS_WT   (WS_XB + XB_SZ)
#define WS_Q    (WS_WT + 4*WT_SZ)
#define WS_K    (WS_Q + QKV_SZ)
#define WS_V    (WS_K + QKV_SZ)
#define WS_AO   (WS_V + QKV_SZ)
#define WS_TOTAL (WS_AO + QKV_SZ)

// log2(e) folded into Q scale so softmax exp() is a bare v_exp_f32
#define QSCALE  0.18033688f   // 0.125 * 1.44269504

__device__ __forceinline__ ushort_t f2bf(float f) {
    unsigned u = __float_as_uint(f);
    u += 0x7FFFu + ((u >> 16) & 1u);
    return (ushort_t)(u >> 16);
}

// raw exp2: single v_exp_f32 (exp2f goes through OCML with fixups)
__device__ __forceinline__ float ex2(float x) {
    float r;
    asm("v_exp_f32 %0, %1" : "=v"(r) : "v"(x));
    return r;
}

// pack two floats -> two bf16 (RNE) in one u32 (v_cvt_pk_bf16_f32)
__device__ __forceinline__ unsigned pk2bf(float a, float b) {
    __hip_bfloat162 h = __float22bfloat162_rn(float2{a, b});
    return *reinterpret_cast<unsigned*>(&h);
}

// async global->LDS, 16B per lane; ldst must be wave-uniform (HW adds lane*16)
__device__ __forceinline__ void gload16(const void* gsrc, void* ldst) {
    __builtin_amdgcn_global_load_lds(
        (const __attribute__((address_space(1))) unsigned int*)gsrc,
        (__attribute__((address_space(3))) unsigned int*)ldst, 16, 0, 0);
}

__global__ __launch_bounds__(256) void k_convert_x(const float* __restrict__ x,
                                                   ushort_t* __restrict__ xb, int n4) {
    int i = blockIdx.x * 256 + threadIdx.x;
    if (i >= n4) return;
    float4 v = ((const float4*)x)[i];
    ushort4 o;
    o.x = f2bf(v.x); o.y = f2bf(v.y); o.z = f2bf(v.z); o.w = f2bf(v.w);
    ((ushort4*)xb)[i] = o;
}

// Wt[n][k] = bf16(W[k][n]), four weights
__global__ __launch_bounds__(256) void k_wt(const float* __restrict__ w0,
                                            const float* __restrict__ w1,
                                            const float* __restrict__ w2,
                                            const float* __restrict__ w3,
                                            ushort_t* __restrict__ wt) {
    __shared__ float tile[32][33];
    int wi = blockIdx.z;
    const float* W = (wi == 0) ? w0 : (wi == 1) ? w1 : (wi == 2) ? w2 : w3;
    ushort_t* out = wt + wi * C_ * C_;
    int k0 = blockIdx.x * 32, n0 = blockIdx.y * 32;
    int tx = threadIdx.x & 31, ty = threadIdx.x >> 5;
#pragma unroll
    for (int i = 0; i < 4; ++i) {
        int kr = ty * 4 + i;
        tile[kr][tx] = W[(k0 + kr) * C_ + n0 + tx];
    }
    __syncthreads();
#pragma unroll
    for (int i = 0; i < 4; ++i) {
        int nr = ty * 4 + i;
        out[(n0 + nr) * C_ + k0 + tx] = f2bf(tile[tx][nr]);
    }
}

// 128x128 tile GEMM, 4 waves (2x2); BK=64; global_load_lds staging with
// inverse-swizzled source (linear LDS dest, swizzled read: rule #21).
// z=0:Q (scaled QSCALE), z=1:K, z=2:V stored transposed [B,H,D,T]
__global__ __launch_bounds__(256) void k_gemm_qkv(
    const ushort_t* __restrict__ Xb, const ushort_t* __restrict__ WtAll,
    const float* __restrict__ bq, const float* __restrict__ bk, const float* __restrict__ bv,
    ushort_t* __restrict__ Qo, ushort_t* __restrict__ Ko, ushort_t* __restrict__ Vo) {
    __shared__ ushort_t lsA[128 * 64];
    __shared__ ushort_t lsB[128 * 64];
    char* lsAb = (char*)lsA;
    char* lsBb = (char*)lsB;
    const int z = blockIdx.z;
    const ushort_t* Wt = WtAll + z * C_ * C_;
    const float* bias = (z == 0) ? bq : (z == 1) ? bk : bv;
    const int m0 = blockIdx.x * 128, n0 = blockIdx.y * 128;
    const int tid = threadIdx.x;
    const int w = tid >> 6, lane = tid & 63, lg = lane >> 4, lr = lane & 15;
    const int wm = w >> 1, wn = w & 1;
    f4v acc[4][4] = {};
    for (int ks = 0; ks < 12; ++ks) {
        const int k0 = ks * 64;
        __syncthreads();
#pragma unroll
        for (int i = 0; i < 4; ++i) {
            int s = tid + 256 * i;
            int r = s >> 3, cs = (s & 7) ^ (r & 7);   // inverse-swizzled source col
            gload16(Xb + (m0 + r) * C_ + k0 + cs * 8, lsAb + i * 4096 + w * 1024);
            gload16(Wt + (n0 + r) * C_ + k0 + cs * 8, lsBb + i * 4096 + w * 1024);
        }
        __syncthreads();
#pragma unroll
        for (int kk = 0; kk < 2; ++kk) {
            bf16x8 af[4], bfr[4];
            const int kb = (kk * 32 + lg * 8) * 2;
#pragma unroll
            for (int i = 0; i < 4; ++i) {
                int ra = wm * 64 + i * 16 + lr;
                af[i] = *(const bf16x8*)(lsAb + ra * 128 + (kb ^ ((ra & 7) << 4)));
                int rb = wn * 64 + i * 16 + lr;
                bfr[i] = *(const bf16x8*)(lsBb + rb * 128 + (kb ^ ((rb & 7) << 4)));
            }
#pragma unroll
            for (int mi = 0; mi < 4; ++mi)
#pragma unroll
                for (int nj = 0; nj < 4; ++nj)
                    acc[mi][nj] = __builtin_amdgcn_mfma_f32_16x16x32_bf16(af[mi], bfr[nj], acc[mi][nj], 0, 0, 0);
        }
    }
    const float scale = (z == 0) ? QSCALE : 1.0f;
    const int mbase = m0 + wm * 64, nbase = n0 + wn * 64;
    if (z < 2) {
        ushort_t* outp = (z == 0) ? Qo : Ko;
#pragma unroll
        for (int mi = 0; mi < 4; ++mi) {
#pragma unroll
            for (int nj = 0; nj < 4; ++nj) {
                int col = nbase + nj * 16 + lr;
                int h = col >> 6, d = col & 63;
                float bv_ = bias[col];
#pragma unroll
                for (int j = 0; j < 4; ++j) {
                    int m = mbase + mi * 16 + lg * 4 + j;
                    int bb = m >> 12, t = m & 4095;
                    outp[((bb * H_ + h) * T_ + t) * D_ + d] = f2bf((acc[mi][nj][j] + bv_) * scale);
                }
            }
        }
    } else {
        // V stored transposed: Vo[((b*H+h)*D + d)*T + t]
#pragma unroll
        for (int mi = 0; mi < 4; ++mi) {
            int m0j = mbase + mi * 16 + lg * 4;
            int bb = m0j >> 12, t0 = m0j & 4095;
#pragma unroll
            for (int nj = 0; nj < 4; ++nj) {
                int col = nbase + nj * 16 + lr;
                int h = col >> 6, d = col & 63;
                float bv_ = bias[col];
                ushort4 pk;
                pk.x = f2bf(acc[mi][nj][0] + bv_);
                pk.y = f2bf(acc[mi][nj][1] + bv_);
                pk.z = f2bf(acc[mi][nj][2] + bv_);
                pk.w = f2bf(acc[mi][nj][3] + bv_);
                *(ushort4*)(Vo + ((size_t)(bb * H_ + h) * D_ + d) * T_ + t0) = pk;
            }
        }
    }
}

// flash attention v3: swapped-operand softmax (T12 structure).
// grid = 1536 blocks big-first (qt = 63 - idx/24, bh = idx%24), 128 threads =
// 2 waves x 32 q-rows; KVBLK=64; V input transposed [B,H,D,T].
// QK^T computed as mfma(K,Q) -> S^T: each lane owns q-row (lr) -> row-reduce is
// 15 in-lane fmax + 2 shfl. PV computed as mfma(V^T,P^T) -> O^T: alpha/l stay
// lane-local (no broadcast shuffles). P goes through per-wave LDS as 4 b64
// writes (cvt_pk packed).
__global__ __launch_bounds__(128, 3) void k_flash(const ushort_t* __restrict__ Q,
                                                  const ushort_t* __restrict__ K,
                                                  const ushort_t* __restrict__ Vt,
                                                  ushort_t* __restrict__ AO) {
    __shared__ ushort_t lsK[64 * 64];
    __shared__ ushort_t lsV[64 * 64];
    __shared__ ushort_t lsP[2 * 32 * 64];
    char* lsKb = (char*)lsK;
    char* lsVb = (char*)lsV;
    const int idx = blockIdx.x;
    const int qt = 63 - idx / 24;   // biggest causal spans first
    const int bh = idx % 24;
    const int b = bh / H_, h = bh % H_;
    const int q0 = qt * 64;
    const int tid = threadIdx.x, w = tid >> 6, lane = tid & 63, lg = lane >> 4, lr = lane & 15;
    char* lsPb = (char*)(lsP + w * 32 * 64);
    const ushort_t* qb = Q + (size_t)bh * T_ * D_;
    const ushort_t* kb = K + (size_t)bh * T_ * D_;
    const ushort_t* vtb = Vt + (size_t)bh * D_ * T_;   // [D][T]
    ushort_t* aob = AO + (size_t)b * T_ * C_ + h * D_;
    const int wave_qmin = q0 + w * 32;

    // Q fragments: 2 frags x 32 q-rows (q = wave_qmin + qf*16 + lr)
    bf16x8 aq[2][2];
#pragma unroll
    for (int qf = 0; qf < 2; ++qf)
#pragma unroll
        for (int kk = 0; kk < 2; ++kk)
            aq[qf][kk] = *(const bf16x8*)(qb + (size_t)(wave_qmin + qf * 16 + lr) * D_ + kk * 32 + lg * 8);

    float m_s[2] = {-1e30f, -1e30f};
    float l_s[2] = {0.f, 0.f};
    f4v o[2][4] = {};   // O^T frags: lane holds O[d = nt*16+lg*4+j][q = ...+qf*16+lr]

    const int ntiles = qt + 1;
    for (int kt = 0; kt < ntiles; ++kt) {
        const int kv0 = kt * 64;
        __syncthreads();
        // stage K rows [kv][d] and V^T rows [d][kv]; linear LDS dest,
        // inverse-swizzled global source (read-side XOR matches)
#pragma unroll
        for (int i = 0; i < 4; ++i) {
            int s = tid + 128 * i;
            int r = s >> 3, cs = (s & 7) ^ (r & 7);
            gload16(kb + (size_t)(kv0 + r) * D_ + cs * 8, lsKb + i * 2048 + w * 1024);
            gload16(vtb + (size_t)r * T_ + kv0 + cs * 8, lsVb + i * 2048 + w * 1024);
        }
        __syncthreads();

        // S^T = K Q^T : sfT[qf][nt][j] = S[k = kv0+nt*16+lg*4+j][q = wqmin+qf*16+lr]
        f4v sfT[2][4] = {};
#pragma unroll
        for (int kk = 0; kk < 2; ++kk) {
            const int kbyte = (kk * 32 + lg * 8) * 2;
            bf16x8 bk_[4];
#pragma unroll
            for (int nt = 0; nt < 4; ++nt) {
                int rk = nt * 16 + lr;
                bk_[nt] = *(const bf16x8*)(lsKb + rk * 128 + (kbyte ^ ((rk & 7) << 4)));
            }
#pragma unroll
            for (int qf = 0; qf < 2; ++qf)
#pragma unroll
                for (int nt = 0; nt < 4; ++nt)
                    sfT[qf][nt] = __builtin_amdgcn_mfma_f32_16x16x32_bf16(bk_[nt], aq[qf][kk], sfT[qf][nt], 0, 0, 0);
        }
        // causal mask (diagonal tiles only), finite sentinel
        if (kv0 + 63 > wave_qmin) {
#pragma unroll
            for (int qf = 0; qf < 2; ++qf) {
                int qg = wave_qmin + qf * 16 + lr;
#pragma unroll
                for (int nt = 0; nt < 4; ++nt)
#pragma unroll
                    for (int j = 0; j < 4; ++j) {
                        int kg = kv0 + nt * 16 + lg * 4 + j;
                        if (kg > qg) sfT[qf][nt][j] = -1e30f;
                    }
            }
        }
        // online softmax: per-lane q-row; reduce across lanes {l, l^16, l^32, l^48}
#pragma unroll
        for (int qf = 0; qf < 2; ++qf) {
            float rm = -1e30f;
#pragma unroll
            for (int nt = 0; nt < 4; ++nt)
#pragma unroll
                for (int j = 0; j < 4; ++j) rm = fmaxf(rm, sfT[qf][nt][j]);
            rm = fmaxf(rm, __shfl_xor(rm, 16));
            rm = fmaxf(rm, __shfl_xor(rm, 32));
            float mo = m_s[qf];
            float mn = fmaxf(mo, rm);
            float al = ex2(mo - mn);
            float rs = 0.f;
            const int prow = qf * 16 + lr;
            const int pswz = (prow & 7) << 4;
#pragma unroll
            for (int nt = 0; nt < 4; ++nt) {
                float p0 = ex2(sfT[qf][nt][0] - mn);
                float p1 = ex2(sfT[qf][nt][1] - mn);
                float p2 = ex2(sfT[qf][nt][2] - mn);
                float p3 = ex2(sfT[qf][nt][3] - mn);
                rs += (p0 + p1) + (p2 + p3);
                uint2 pk;
                pk.x = pk2bf(p0, p1);
                pk.y = pk2bf(p2, p3);
                *(uint2*)(lsPb + prow * 128 + ((nt * 32 + lg * 8) ^ pswz)) = pk;
            }
            rs += __shfl_xor(rs, 16);
            rs += __shfl_xor(rs, 32);
            l_s[qf] = l_s[qf] * al + rs;
            m_s[qf] = mn;
#pragma unroll
            for (int nt = 0; nt < 4; ++nt)
#pragma unroll
                for (int j = 0; j < 4; ++j) o[qf][nt][j] *= al;
        }
        // O^T += V^T P^T : o[qf][nt] accumulates O[d-block nt][q(lane)]
#pragma unroll
        for (int kk = 0; kk < 2; ++kk) {
            const int kvbyte = (kk * 32 + lg * 8) * 2;
            bf16x8 bv_[4], ap[2];
#pragma unroll
            for (int nt = 0; nt < 4; ++nt) {
                int rd = nt * 16 + lr;
                bv_[nt] = *(const bf16x8*)(lsVb + rd * 128 + (kvbyte ^ ((rd & 7) << 4)));
            }
#pragma unroll
            for (int qf = 0; qf < 2; ++qf) {
                int rp = qf * 16 + lr;
                ap[qf] = *(const bf16x8*)(lsPb + rp * 128 + (kvbyte ^ ((rp & 7) << 4)));
            }
#pragma unroll
            for (int qf = 0; qf < 2; ++qf)
#pragma unroll
                for (int nt = 0; nt < 4; ++nt)
                    o[qf][nt] = __builtin_amdgcn_mfma_f32_16x16x32_bf16(bv_[nt], ap[qf], o[qf][nt], 0, 0, 0);
        }
    }
    // epilogue: normalize (all lane-local) + store O to [B,T,C] bf16
#pragma unroll
    for (int qf = 0; qf < 2; ++qf) {
        float inv = 1.f / l_s[qf];
        int qg = wave_qmin + qf * 16 + lr;
        ushort_t* orow = aob + (size_t)qg * C_;
#pragma unroll
        for (int nt = 0; nt < 4; ++nt)
#pragma unroll
            for (int j = 0; j < 4; ++j) {
                int d = nt * 16 + lg * 4 + j;
                orow[d] = f2bf(o[qf][nt][j] * inv);
            }
    }
}

// final projection: fp32 out = AO @ Wo^T(stored) + bo
__global__ __launch_bounds__(256) void k_gemm_out(const ushort_t* __restrict__ Ab,
                                                  const ushort_t* __restrict__ Wt,
                                                  const float* __restrict__ bo,
                                                  float* __restrict__ Out) {
    __shared__ ushort_t lsA[128 * 64];
    __shared__ ushort_t lsB[128 * 64];
    char* lsAb = (char*)lsA;
    char* lsBb = (char*)lsB;
    const int m0 = blockIdx.x * 128, n0 = blockIdx.y * 128;
    const int tid = threadIdx.x;
    const int w = tid >> 6, lane = tid & 63, lg = lane >> 4, lr = lane & 15;
    const int wm = w >> 1, wn = w & 1;
    f4v acc[4][4] = {};
    for (int ks = 0; ks < 12; ++ks) {
        const int k0 = ks * 64;
        __syncthreads();
#pragma unroll
        for (int i = 0; i < 4; ++i) {
            int s = tid + 256 * i;
            int r = s >> 3, cs = (s & 7) ^ (r & 7);
            gload16(Ab + (m0 + r) * C_ + k0 + cs * 8, lsAb + i * 4096 + w * 1024);
            gload16(Wt + (n0 + r) * C_ + k0 + cs * 8, lsBb + i * 4096 + w * 1024);
        }
        __syncthreads();
#pragma unroll
        for (int kk = 0; kk < 2; ++kk) {
            bf16x8 af[4], bfr[4];
            const int kb = (kk * 32 + lg * 8) * 2;
#pragma unroll
            for (int i = 0; i < 4; ++i) {
                int ra = wm * 64 + i * 16 + lr;
                af[i] = *(const bf16x8*)(lsAb + ra * 128 + (kb ^ ((ra & 7) << 4)));
                int rb = wn * 64 + i * 16 + lr;
                bfr[i] = *(const bf16x8*)(lsBb + rb * 128 + (kb ^ ((rb & 7) << 4)));
            }
#pragma unroll
            for (int mi = 0; mi < 4; ++mi)
#pragma unroll
                for (int nj = 0; nj < 4; ++nj)
                    acc[mi][nj] = __builtin_amdgcn_mfma_f32_16x16x32_bf16(af[mi], bfr[nj], acc[mi][nj], 0, 0, 0);
        }
    }
    const int mbase = m0 + wm * 64, nbase = n0 + wn * 64;
#pragma unroll
    for (int mi = 0; mi < 4; ++mi) {
#pragma unroll
        for (int nj = 0; nj < 4; ++nj) {
            int col = nbase + nj * 16 + lr;
            float bv_ = bo[col];
#pragma unroll
            for (int j = 0; j < 4; ++j) {
                int m = mbase + mi * 16 + lg * 4 + j;
                Out[(size_t)m * C_ + col] = acc[mi][nj][j] + bv_;
            }
        }
    }
}

extern "C" void kernel_launch(void* const* d_in, const int* in_sizes, int n_in,
                              void* d_out, int out_size, void* d_ws, size_t ws_size,
                              hipStream_t stream) {
    const float* x  = (const float*)d_in[0];
    const float* Wq = (const float*)d_in[1];
    const float* bq = (const float*)d_in[2];
    const float* Wk = (const float*)d_in[3];
    const float* bk = (const float*)d_in[4];
    const float* Wv = (const float*)d_in[5];
    const float* bv = (const float*)d_in[6];
    const float* Wo = (const float*)d_in[7];
    const float* bo = (const float*)d_in[8];
    float* out = (float*)d_out;
    char* ws = (char*)d_ws;
    if (ws_size < (size_t)WS_TOTAL) return;

    ushort_t* Xb = (ushort_t*)(ws + WS_XB);
    ushort_t* Wt = (ushort_t*)(ws + WS_WT);
    ushort_t* Qb = (ushort_t*)(ws + WS_Q);
    ushort_t* Kb = (ushort_t*)(ws + WS_K);
    ushort_t* Vb = (ushort_t*)(ws + WS_V);
    ushort_t* Ao = (ushort_t*)(ws + WS_AO);

    k_convert_x<<<dim3(BT_ * C_ / 4 / 256), 256, 0, stream>>>(x, Xb, BT_ * C_ / 4);
    k_wt<<<dim3(24, 24, 4), 256, 0, stream>>>(Wq, Wk, Wv, Wo, Wt);
    k_gemm_qkv<<<dim3(64, 6, 3), 256, 0, stream>>>(Xb, Wt, bq, bk, bv, Qb, Kb, Vb);
    k_flash<<<dim3(64 * 24), 128, 0, stream>>>(Qb, Kb, Vb, Ao);
    k_gemm_out<<<dim3(64, 6), 256, 0, stream>>>(Ao, Wt + 3 * C_ * C_, bo, out);
}

// Round 11
// 284.700 us; speedup vs baseline: 1.2045x; 1.0181x over previous
//
#include <hip/hip_runtime.h>
#include <hip/hip_bf16.h>

typedef unsigned short ushort_t;
typedef __bf16 bf16x8 __attribute__((ext_vector_type(8)));
typedef float f4v __attribute__((ext_vector_type(4)));
typedef float f16v __attribute__((ext_vector_type(16)));

#define B_ 2
#define T_ 4096
#define C_ 768
#define H_ 12
#define D_ 64
#define BT_ (B_*T_)

// workspace layout (bytes)
#define XB_SZ   (BT_*C_*2)
#define WT_SZ   (C_*C_*2)
#define QKV_SZ  (BT_*C_*2)
#define WS_XB   0
#define WS_WT   (WS_XB + XB_SZ)
#define WS_Q    (WS_WT + 4*WT_SZ)
#define WS_K    (WS_Q + QKV_SZ)
#define WS_V    (WS_K + QKV_SZ)
#define WS_AO   (WS_V + QKV_SZ)
#define WS_TOTAL (WS_AO + QKV_SZ)

// log2(e) folded into Q scale so softmax exp() is a bare v_exp_f32
#define QSCALE  0.18033688f   // 0.125 * 1.44269504

__device__ __forceinline__ ushort_t f2bf(float f) {
    unsigned u = __float_as_uint(f);
    u += 0x7FFFu + ((u >> 16) & 1u);
    return (ushort_t)(u >> 16);
}

// raw exp2: single v_exp_f32 (exp2f goes through OCML with fixups)
__device__ __forceinline__ float ex2(float x) {
    float r;
    asm("v_exp_f32 %0, %1" : "=v"(r) : "v"(x));
    return r;
}

// pack two f32 -> two bf16 (RNE) in one u32
__device__ __forceinline__ unsigned cvtpk(float a, float b) {
    unsigned r;
    asm("v_cvt_pk_bf16_f32 %0, %1, %2" : "=v"(r) : "v"(a), "v"(b));
    return r;
}

// async global->LDS, 16B per lane; ldst must be wave-uniform (HW adds lane*16)
__device__ __forceinline__ void gload16(const void* gsrc, void* ldst) {
    __builtin_amdgcn_global_load_lds(
        (const __attribute__((address_space(1))) unsigned int*)gsrc,
        (__attribute__((address_space(3))) unsigned int*)ldst, 16, 0, 0);
}

__global__ __launch_bounds__(256) void k_convert_x(const float* __restrict__ x,
                                                   ushort_t* __restrict__ xb, int n4) {
    int i = blockIdx.x * 256 + threadIdx.x;
    if (i >= n4) return;
    float4 v = ((const float4*)x)[i];
    ushort4 o;
    o.x = f2bf(v.x); o.y = f2bf(v.y); o.z = f2bf(v.z); o.w = f2bf(v.w);
    ((ushort4*)xb)[i] = o;
}

// Wt[n][k] = bf16(W[k][n]), four weights
__global__ __launch_bounds__(256) void k_wt(const float* __restrict__ w0,
                                            const float* __restrict__ w1,
                                            const float* __restrict__ w2,
                                            const float* __restrict__ w3,
                                            ushort_t* __restrict__ wt) {
    __shared__ float tile[32][33];
    int wi = blockIdx.z;
    const float* W = (wi == 0) ? w0 : (wi == 1) ? w1 : (wi == 2) ? w2 : w3;
    ushort_t* out = wt + wi * C_ * C_;
    int k0 = blockIdx.x * 32, n0 = blockIdx.y * 32;
    int tx = threadIdx.x & 31, ty = threadIdx.x >> 5;
#pragma unroll
    for (int i = 0; i < 4; ++i) {
        int kr = ty * 4 + i;
        tile[kr][tx] = W[(k0 + kr) * C_ + n0 + tx];
    }
    __syncthreads();
#pragma unroll
    for (int i = 0; i < 4; ++i) {
        int nr = ty * 4 + i;
        out[(n0 + nr) * C_ + k0 + tx] = f2bf(tile[tx][nr]);
    }
}

// 128x128 tile GEMM, 4 waves (2x2); BK=64; global_load_lds staging with
// inverse-swizzled source (linear LDS dest, swizzled read: rule #21).
// z=0:Q (scaled QSCALE), z=1:K, z=2:V stored transposed [B,H,D,T]
__global__ __launch_bounds__(256) void k_gemm_qkv(
    const ushort_t* __restrict__ Xb, const ushort_t* __restrict__ WtAll,
    const float* __restrict__ bq, const float* __restrict__ bk, const float* __restrict__ bv,
    ushort_t* __restrict__ Qo, ushort_t* __restrict__ Ko, ushort_t* __restrict__ Vo) {
    __shared__ ushort_t lsA[128 * 64];
    __shared__ ushort_t lsB[128 * 64];
    char* lsAb = (char*)lsA;
    char* lsBb = (char*)lsB;
    const int z = blockIdx.z;
    const ushort_t* Wt = WtAll + z * C_ * C_;
    const float* bias = (z == 0) ? bq : (z == 1) ? bk : bv;
    const int m0 = blockIdx.x * 128, n0 = blockIdx.y * 128;
    const int tid = threadIdx.x;
    const int w = tid >> 6, lane = tid & 63, lg = lane >> 4, lr = lane & 15;
    const int wm = w >> 1, wn = w & 1;
    f4v acc[4][4] = {};
    for (int ks = 0; ks < 12; ++ks) {
        const int k0 = ks * 64;
        __syncthreads();
#pragma unroll
        for (int i = 0; i < 4; ++i) {
            int s = tid + 256 * i;
            int r = s >> 3, cs = (s & 7) ^ (r & 7);   // inverse-swizzled source col
            gload16(Xb + (m0 + r) * C_ + k0 + cs * 8, lsAb + i * 4096 + w * 1024);
            gload16(Wt + (n0 + r) * C_ + k0 + cs * 8, lsBb + i * 4096 + w * 1024);
        }
        __syncthreads();
#pragma unroll
        for (int kk = 0; kk < 2; ++kk) {
            bf16x8 af[4], bfr[4];
            const int kb = (kk * 32 + lg * 8) * 2;
#pragma unroll
            for (int i = 0; i < 4; ++i) {
                int ra = wm * 64 + i * 16 + lr;
                af[i] = *(const bf16x8*)(lsAb + ra * 128 + (kb ^ ((ra & 7) << 4)));
                int rb = wn * 64 + i * 16 + lr;
                bfr[i] = *(const bf16x8*)(lsBb + rb * 128 + (kb ^ ((rb & 7) << 4)));
            }
#pragma unroll
            for (int mi = 0; mi < 4; ++mi)
#pragma unroll
                for (int nj = 0; nj < 4; ++nj)
                    acc[mi][nj] = __builtin_amdgcn_mfma_f32_16x16x32_bf16(af[mi], bfr[nj], acc[mi][nj], 0, 0, 0);
        }
    }
    const float scale = (z == 0) ? QSCALE : 1.0f;
    const int mbase = m0 + wm * 64, nbase = n0 + wn * 64;
    if (z < 2) {
        ushort_t* outp = (z == 0) ? Qo : Ko;
#pragma unroll
        for (int mi = 0; mi < 4; ++mi) {
#pragma unroll
            for (int nj = 0; nj < 4; ++nj) {
                int col = nbase + nj * 16 + lr;
                int h = col >> 6, d = col & 63;
                float bv_ = bias[col];
#pragma unroll
                for (int j = 0; j < 4; ++j) {
                    int m = mbase + mi * 16 + lg * 4 + j;
                    int bb = m >> 12, t = m & 4095;
                    outp[((bb * H_ + h) * T_ + t) * D_ + d] = f2bf((acc[mi][nj][j] + bv_) * scale);
                }
            }
        }
    } else {
        // V stored transposed: Vo[((b*H+h)*D + d)*T + t]
#pragma unroll
        for (int mi = 0; mi < 4; ++mi) {
            int m0j = mbase + mi * 16 + lg * 4;
            int bb = m0j >> 12, t0 = m0j & 4095;
#pragma unroll
            for (int nj = 0; nj < 4; ++nj) {
                int col = nbase + nj * 16 + lr;
                int h = col >> 6, d = col & 63;
                float bv_ = bias[col];
                ushort4 pk;
                pk.x = f2bf(acc[mi][nj][0] + bv_);
                pk.y = f2bf(acc[mi][nj][1] + bv_);
                pk.z = f2bf(acc[mi][nj][2] + bv_);
                pk.w = f2bf(acc[mi][nj][3] + bv_);
                *(ushort4*)(Vo + ((size_t)(bb * H_ + h) * D_ + d) * T_ + t0) = pk;
            }
        }
    }
}

// flash attention v4: 32x32x16 MFMA, fully in-register P (cvt_pk + permlane32_swap),
// double-buffered K/V with prefetch-before-compute (one barrier per tile).
// grid = 1536 blocks big-first (qt = 63 - idx/24, bh = idx%24), 128 threads =
// 2 waves x 32 q each; KVBLK=64; V input transposed [B,H,D,T].
// S^T = mfma32(K, Q^T): lane (hf=l>>5) holds S[kv = kb*32 + (r&3)+8(r>>2)+4hf][q = l&31].
// PV: O^T += mfma32(V^T, P^T); P^T B-frag built in-register.
__global__ __launch_bounds__(128) void k_flash(const ushort_t* __restrict__ Q,
                                               const ushort_t* __restrict__ K,
                                               const ushort_t* __restrict__ Vt,
                                               ushort_t* __restrict__ AO) {
    __shared__ ushort_t lsK[2][64 * 64];
    __shared__ ushort_t lsV[2][64 * 64];
    const int idx = blockIdx.x;
    const int qt = 63 - idx / 24;   // biggest causal spans first
    const int bh = idx % 24;
    const int b = bh / H_, h = bh % H_;
    const int q0 = qt * 64;
    const int tid = threadIdx.x, w = tid >> 6;
    const int lane = tid & 63, l31 = lane & 31, hf = lane >> 5;
    const ushort_t* qb = Q + (size_t)bh * T_ * D_;
    const ushort_t* kb = K + (size_t)bh * T_ * D_;
    const ushort_t* vtb = Vt + (size_t)bh * D_ * T_;   // [D][T]
    const int qw = q0 + w * 32;
    const int myq = qw + l31;      // this lane's q column

    // Q^T B-frags: aq[c] = Q[myq][c*16 + hf*8 + e], e=0..7
    bf16x8 aq[4];
#pragma unroll
    for (int c = 0; c < 4; ++c)
        aq[c] = *(const bf16x8*)(qb + (size_t)myq * D_ + c * 16 + hf * 8);

    float m_s = -1e30f, l_s = 0.f;
    f16v o[2] = {};   // o[db]: O^T[d = db*32 + (r&3)+8(r>>2)+4hf][q = myq]

    const int ntiles = qt + 1;

#define STAGE(bufi, kt_) do {                                                   \
        const int kv0s = (kt_) * 64;                                            \
        char* dK = (char*)lsK[bufi];                                            \
        char* dV = (char*)lsV[bufi];                                            \
        _Pragma("unroll")                                                       \
        for (int i_ = 0; i_ < 4; ++i_) {                                        \
            int s_ = tid + 128 * i_;                                            \
            int r_ = s_ >> 3, cs_ = (s_ & 7) ^ (r_ & 7);                        \
            gload16(kb + (size_t)(kv0s + r_) * D_ + cs_ * 8, dK + i_ * 2048 + w * 1024); \
            gload16(vtb + (size_t)r_ * T_ + kv0s + cs_ * 8, dV + i_ * 2048 + w * 1024);  \
        }                                                                       \
    } while (0)

    STAGE(0, 0);
    __syncthreads();

    for (int kt = 0; kt < ntiles; ++kt) {
        const int cur = kt & 1;
        if (kt + 1 < ntiles) STAGE(cur ^ 1, kt + 1);   // prefetch next tile
        const char* sK = (const char*)lsK[cur];
        const char* sV = (const char*)lsV[cur];
        const int kv0 = kt * 64;

        // S^T: 2 kv-blocks of 32
        f16v sT[2] = {};
#pragma unroll
        for (int kb_ = 0; kb_ < 2; ++kb_) {
            const int row = kb_ * 32 + l31;
            const int swz = (row & 7) << 4;
#pragma unroll
            for (int c = 0; c < 4; ++c) {
                bf16x8 ak = *(const bf16x8*)(sK + row * 128 + ((c * 32 + hf * 16) ^ swz));
                sT[kb_] = __builtin_amdgcn_mfma_f32_32x32x16_bf16(ak, aq[c], sT[kb_], 0, 0, 0);
            }
        }
        // causal mask on diagonal tiles (finite sentinel)
        if (kv0 + 63 > qw) {
#pragma unroll
            for (int kb_ = 0; kb_ < 2; ++kb_)
#pragma unroll
                for (int r = 0; r < 16; ++r) {
                    int kv = kv0 + kb_ * 32 + (r & 3) + 8 * (r >> 2) + 4 * hf;
                    if (kv > myq) sT[kb_][r] = -1e30f;
                }
        }
        // online softmax: own 32 values, cross-half via one shfl_xor(32)
        float rm = -1e30f;
#pragma unroll
        for (int kb_ = 0; kb_ < 2; ++kb_)
#pragma unroll
            for (int r = 0; r < 16; ++r) rm = fmaxf(rm, sT[kb_][r]);
        rm = fmaxf(rm, __shfl_xor(rm, 32));
        const float mn = fmaxf(m_s, rm);
        const float al = ex2(m_s - mn);
        float rs = 0.f;
#pragma unroll
        for (int kb_ = 0; kb_ < 2; ++kb_)
#pragma unroll
            for (int r = 0; r < 16; ++r) {
                float p = ex2(sT[kb_][r] - mn);
                sT[kb_][r] = p;      // reuse sT as exp storage
                rs += p;
            }
        rs += __shfl_xor(rs, 32);
        l_s = l_s * al + rs;
        m_s = mn;
#pragma unroll
        for (int db = 0; db < 2; ++db)
#pragma unroll
            for (int r = 0; r < 16; ++r) o[db][r] *= al;

        // P^T B-frags fully in-register: per 16-kv chunk c16 = kb_*2+cc:
        // v0 <- swap(pk(r0,r1), pk(r4,r5)); v1 <- swap(pk(r2,r3), pk(r6,r7))
        unsigned pb[4][4];
#pragma unroll
        for (int kb_ = 0; kb_ < 2; ++kb_) {
#pragma unroll
            for (int cc = 0; cc < 2; ++cc) {
                const int rb = cc * 8;
                unsigned a0 = cvtpk(sT[kb_][rb + 0], sT[kb_][rb + 1]);
                unsigned b0 = cvtpk(sT[kb_][rb + 4], sT[kb_][rb + 5]);
                unsigned a1 = cvtpk(sT[kb_][rb + 2], sT[kb_][rb + 3]);
                unsigned b1 = cvtpk(sT[kb_][rb + 6], sT[kb_][rb + 7]);
                asm("v_permlane32_swap_b32 %0, %1" : "+v"(a0), "+v"(b0));
                asm("v_permlane32_swap_b32 %0, %1" : "+v"(a1), "+v"(b1));
                const int c16 = kb_ * 2 + cc;
                pb[c16][0] = a0; pb[c16][1] = a1; pb[c16][2] = b0; pb[c16][3] = b1;
            }
        }
        // O^T += V^T P^T
#pragma unroll
        for (int db = 0; db < 2; ++db) {
            const int row = db * 32 + l31;
            const int swz = (row & 7) << 4;
#pragma unroll
            for (int c16 = 0; c16 < 4; ++c16) {
                bf16x8 av = *(const bf16x8*)(sV + row * 128 + ((c16 * 32 + hf * 16) ^ swz));
                o[db] = __builtin_amdgcn_mfma_f32_32x32x16_bf16(av, *(const bf16x8*)&pb[c16][0], o[db], 0, 0, 0);
            }
        }
        __syncthreads();   // implicit vmcnt(0)+lgkmcnt(0): prefetch landed, all waves done with cur
    }
#undef STAGE

    // epilogue: normalize (lane-local) + store O to [B,T,C] bf16
    const float inv = 1.f / l_s;
    ushort_t* orow = AO + ((size_t)b * T_ + myq) * C_ + h * D_;
#pragma unroll
    for (int db = 0; db < 2; ++db)
#pragma unroll
        for (int g = 0; g < 4; ++g) {
            ushort4 pk;
            pk.x = f2bf(o[db][g * 4 + 0] * inv);
            pk.y = f2bf(o[db][g * 4 + 1] * inv);
            pk.z = f2bf(o[db][g * 4 + 2] * inv);
            pk.w = f2bf(o[db][g * 4 + 3] * inv);
            *(ushort4*)(orow + db * 32 + g * 8 + hf * 4) = pk;
        }
}

// final projection: fp32 out = AO @ Wo^T(stored) + bo
__global__ __launch_bounds__(256) void k_gemm_out(const ushort_t* __restrict__ Ab,
                                                  const ushort_t* __restrict__ Wt,
                                                  const float* __restrict__ bo,
                                                  float* __restrict__ Out) {
    __shared__ ushort_t lsA[128 * 64];
    __shared__ ushort_t lsB[128 * 64];
    char* lsAb = (char*)lsA;
    char* lsBb = (char*)lsB;
    const int m0 = blockIdx.x * 128, n0 = blockIdx.y * 128;
    const int tid = threadIdx.x;
    const int w = tid >> 6, lane = tid & 63, lg = lane >> 4, lr = lane & 15;
    const int wm = w >> 1, wn = w & 1;
    f4v acc[4][4] = {};
    for (int ks = 0; ks < 12; ++ks) {
        const int k0 = ks * 64;
        __syncthreads();
#pragma unroll
        for (int i = 0; i < 4; ++i) {
            int s = tid + 256 * i;
            int r = s >> 3, cs = (s & 7) ^ (r & 7);
            gload16(Ab + (m0 + r) * C_ + k0 + cs * 8, lsAb + i * 4096 + w * 1024);
            gload16(Wt + (n0 + r) * C_ + k0 + cs * 8, lsBb + i * 4096 + w * 1024);
        }
        __syncthreads();
#pragma unroll
        for (int kk = 0; kk < 2; ++kk) {
            bf16x8 af[4], bfr[4];
            const int kb = (kk * 32 + lg * 8) * 2;
#pragma unroll
            for (int i = 0; i < 4; ++i) {
                int ra = wm * 64 + i * 16 + lr;
                af[i] = *(const bf16x8*)(lsAb + ra * 128 + (kb ^ ((ra & 7) << 4)));
                int rb = wn * 64 + i * 16 + lr;
                bfr[i] = *(const bf16x8*)(lsBb + rb * 128 + (kb ^ ((rb & 7) << 4)));
            }
#pragma unroll
            for (int mi = 0; mi < 4; ++mi)
#pragma unroll
                for (int nj = 0; nj < 4; ++nj)
                    acc[mi][nj] = __builtin_amdgcn_mfma_f32_16x16x32_bf16(af[mi], bfr[nj], acc[mi][nj], 0, 0, 0);
        }
    }
    const int mbase = m0 + wm * 64, nbase = n0 + wn * 64;
#pragma unroll
    for (int mi = 0; mi < 4; ++mi) {
#pragma unroll
        for (int nj = 0; nj < 4; ++nj) {
            int col = nbase + nj * 16 + lr;
            float bv_ = bo[col];
#pragma unroll
            for (int j = 0; j < 4; ++j) {
                int m = mbase + mi * 16 + lg * 4 + j;
                Out[(size_t)m * C_ + col] = acc[mi][nj][j] + bv_;
            }
        }
    }
}

extern "C" void kernel_launch(void* const* d_in, const int* in_sizes, int n_in,
                              void* d_out, int out_size, void* d_ws, size_t ws_size,
                              hipStream_t stream) {
    const float* x  = (const float*)d_in[0];
    const float* Wq = (const float*)d_in[1];
    const float* bq = (const float*)d_in[2];
    const float* Wk = (const float*)d_in[3];
    const float* bk = (const float*)d_in[4];
    const float* Wv = (const float*)d_in[5];
    const float* bv = (const float*)d_in[6];
    const float* Wo = (const float*)d_in[7];
    const float* bo = (const float*)d_in[8];
    float* out = (float*)d_out;
    char* ws = (char*)d_ws;
    if (ws_size < (size_t)WS_TOTAL) return;

    ushort_t* Xb = (ushort_t*)(ws + WS_XB);
    ushort_t* Wt = (ushort_t*)(ws + WS_WT);
    ushort_t* Qb = (ushort_t*)(ws + WS_Q);
    ushort_t* Kb = (ushort_t*)(ws + WS_K);
    ushort_t* Vb = (ushort_t*)(ws + WS_V);
    ushort_t* Ao = (ushort_t*)(ws + WS_AO);

    k_convert_x<<<dim3(BT_ * C_ / 4 / 256), 256, 0, stream>>>(x, Xb, BT_ * C_ / 4);
    k_wt<<<dim3(24, 24, 4), 256, 0, stream>>>(Wq, Wk, Wv, Wo, Wt);
    k_gemm_qkv<<<dim3(64, 6, 3), 256, 0, stream>>>(Xb, Wt, bq, bk, bv, Qb, Kb, Vb);
    k_flash<<<dim3(64 * 24), 128, 0, stream>>>(Qb, Kb, Vb, Ao);
    k_gemm_out<<<dim3(64, 6), 256, 0, stream>>>(Ao, Wt + 3 * C_ * C_, bo, out);
}